// Round 10
// baseline (399.668 us; speedup 1.0000x reference)
//
#include <hip/hip_runtime.h>

typedef __bf16 bf16_t;
typedef bf16_t bf16x8 __attribute__((ext_vector_type(8)));
typedef float f32x4 __attribute__((ext_vector_type(4)));
typedef short s16x4 __attribute__((ext_vector_type(4)));

#define NSEQ 2048
#define EMB 512
#define HEADS 8
#define HD 64
#define BATCH 4
#define LOG2E 1.4426950408889634f

#define MFMA16(a, b, c) __builtin_amdgcn_mfma_f32_16x16x32_bf16(a, b, c, 0, 0, 0)
// K=16 bf16 MFMA: A,B = v4i16 (4 bf16), lane: m/n=l15, k=quad*4+j
#define MFMA1K(a, b, c) __builtin_amdgcn_mfma_f32_16x16x16bf16_1k(a, b, c, 0, 0, 0)

// Fragment-major layouts (frag = 64 lanes x 8 bf16, contiguous 1 KB):
//   Kf[((bh*128 + kt16)*2 + kk)*512 + lane*8 + j]
//       = K[bh][key = kt16*16 + (lane&15)][d = kk*32 + (lane>>4)*8 + j]
//   Vf[((bh*64 + kt32)*4 + dt)*512 + lane*8 + j']   (V^T A-frag pairs, K=16)
//       = V[bh][key = kt32*32 + (j'>>2)*16 + (lane>>4)*4 + (j'&3)][d = dt*16 + (lane&15)]

// ---------------------------------------------------------------------------
// Fused K/V projection GEMM with inline fp32->bf16 convert (unchanged R9).
// ---------------------------------------------------------------------------
__global__ __launch_bounds__(256, 2) void proj_kernel(
    const float* __restrict__ x,
    const float* __restrict__ Wk, const float* __restrict__ bk,
    const float* __restrict__ Wv, const float* __restrict__ bv,
    bf16_t* __restrict__ Kf, bf16_t* __restrict__ Vf)
{
  __shared__ union {
    struct {
      __align__(16) bf16_t A[2][128][40];   // [kk-half][row][32 el + pad]
      __align__(16) bf16_t B[2][128][40];
    } s;
    __align__(16) bf16_t T[128][136];       // epilogue relayout buffer
  } u;

  const int t    = threadIdx.x;
  const int w    = t >> 6;
  const int lane = t & 63;
  const int quad = lane >> 4;
  const int l15  = lane & 15;
  const int wr   = w >> 1, wc = w & 1;
  const int m0   = blockIdx.x * 128;
  const int n0   = blockIdx.y * 128;        // stacked feature base 0..896
  const int zz   = (blockIdx.y >= 4);       // 0: K-features, 1: V-features
  const float* __restrict__ W = zz ? Wv : Wk;
  const int nW = n0 - zz * 512;             // row base within W

  const int sr = t >> 3;        // staging row 0..31 (x4 groups)
  const int sj = t & 7;         // 8-el chunk 0..7 within 64-el k slab
  const int sb = sj >> 2, sc = (sj & 3) * 8;

  float4 pa[4][2], pb[4][2];
  auto prefetch = [&](int k0) {
#pragma unroll
    for (int i = 0; i < 4; ++i) {
      const float* xa = x + (size_t)(m0 + sr + i * 32) * EMB + k0 + sj * 8;
      const float* wa = W + (size_t)(nW + sr + i * 32) * EMB + k0 + sj * 8;
      pa[i][0] = *(const float4*)xa; pa[i][1] = *(const float4*)(xa + 4);
      pb[i][0] = *(const float4*)wa; pb[i][1] = *(const float4*)(wa + 4);
    }
  };
  auto pack8 = [](float4 a, float4 b) -> bf16x8 {
    bf16x8 v;
    v[0] = (bf16_t)a.x; v[1] = (bf16_t)a.y; v[2] = (bf16_t)a.z; v[3] = (bf16_t)a.w;
    v[4] = (bf16_t)b.x; v[5] = (bf16_t)b.y; v[6] = (bf16_t)b.z; v[7] = (bf16_t)b.w;
    return v;
  };

  f32x4 acc[4][4] = {};
  prefetch(0);

  for (int it = 0; it < 8; ++it) {
    __syncthreads();
#pragma unroll
    for (int i = 0; i < 4; ++i) {
      *(bf16x8*)(&u.s.A[sb][sr + i * 32][sc]) = pack8(pa[i][0], pa[i][1]);
      *(bf16x8*)(&u.s.B[sb][sr + i * 32][sc]) = pack8(pb[i][0], pb[i][1]);
    }
    __syncthreads();
    if (it < 7) prefetch((it + 1) * 64);

    bf16x8 af[4][2], bf[4][2];
#pragma unroll
    for (int mt = 0; mt < 4; ++mt)
#pragma unroll
      for (int kk = 0; kk < 2; ++kk)
        af[mt][kk] = *(const bf16x8*)(&u.s.A[kk][wr * 64 + mt * 16 + l15][quad * 8]);
#pragma unroll
    for (int nt = 0; nt < 4; ++nt)
#pragma unroll
      for (int kk = 0; kk < 2; ++kk)
        bf[nt][kk] = *(const bf16x8*)(&u.s.B[kk][wc * 64 + nt * 16 + l15][quad * 8]);
#pragma unroll
    for (int kk = 0; kk < 2; ++kk)
#pragma unroll
      for (int mt = 0; mt < 4; ++mt)
#pragma unroll
        for (int nt = 0; nt < 4; ++nt)
          acc[mt][nt] = MFMA16(af[mt][kk], bf[nt][kk], acc[mt][nt]);
  }

  __syncthreads();  // staging LDS -> relayout buffer reuse

  // Stage 1: +bias, bf16, into LDS (K: row-major [n][feat]; V: [feat][n]).
#pragma unroll
  for (int mt = 0; mt < 4; ++mt) {
#pragma unroll
    for (int nt = 0; nt < 4; ++nt) {
      const int F = wc * 64 + nt * 16 + l15;       // local feature 0..127
      const int c = n0 + F;                        // stacked feature 0..1023
      const float bb = zz ? bv[c - 512] : bk[c];
#pragma unroll
      for (int reg = 0; reg < 4; ++reg) {
        const int R = wr * 64 + mt * 16 + quad * 4 + reg;  // local row 0..127
        const float v = acc[mt][nt][reg] + bb;
        if (!zz) u.T[R][F] = (bf16_t)v;
        else     u.T[F][R] = (bf16_t)v;
      }
    }
  }
  __syncthreads();

  // Stage 2: fragment-major coalesced stores (1 KB per wave-store).
  if (!zz) {
    // 32 frags: hL(2) x kk(2) x ktl(8)
#pragma unroll
    for (int i = 0; i < 8; ++i) {
      const int fi  = i * 4 + w;
      const int hL  = fi >> 4, kk = (fi >> 3) & 1, ktl = fi & 7;
      const bf16x8 v = *(const bf16x8*)(&u.T[ktl * 16 + l15][hL * 64 + kk * 32 + quad * 8]);
      const int gr = m0 + ktl * 16 + l15;          // global key row
      const int b = gr >> 11, n = gr & (NSEQ - 1);
      const int bh = b * HEADS + (n0 >> 6) + hL;
      bf16_t* dst = Kf + (((size_t)(bh * 128 + (n >> 4)) * 2 + kk)) * 512 + lane * 8;
      *(bf16x8*)dst = v;
    }
  } else {
    // 32 frags: hL(2) x dt(4) x k32l(4); K=16 A-frag pair layout.
#pragma unroll
    for (int i = 0; i < 8; ++i) {
      const int fi   = i * 4 + w;
      const int hL   = fi >> 4, dt = (fi >> 2) & 3, k32l = fi & 3;
      const int F = hL * 64 + dt * 16 + l15;
      union { bf16_t h[8]; bf16x8 v; } pk2;
#pragma unroll
      for (int jt = 0; jt < 2; ++jt)
        *(uint2*)(&pk2.h[jt * 4]) =
            *(const uint2*)(&u.T[F][k32l * 32 + jt * 16 + quad * 4]);
      const int gr = m0 + k32l * 32;               // key base (same b for block)
      const int b = gr >> 11, n = gr & (NSEQ - 1);
      const int bh = b * HEADS + ((n0 - 512) >> 6) + hL;
      bf16_t* dst = Vf + (((size_t)(bh * 64 + (n >> 5)) * 4 + dt)) * 512 + lane * 8;
      *(bf16x8*)dst = pk2.v;
    }
  }
}

// ---------------------------------------------------------------------------
// Flash attention, Q = K, fixed max, S^T trick, register-only PV (R9 math,
// byte-identical). R10: 4-WAY key split for occupancy — waves are fully
// independent (no staging/no barriers), so wave count is free. Block = 4
// waves = 64 qrows x 4 disjoint key-quarters; grid (32 bh, 32 mtile) = 1024
// blocks -> 4 blocks/CU = 4 waves/SIMD (VGPR ~124 <= 128). exp-VALU of one
// wave now overlaps S/PV-MFMA of the others. 2-level LDS tree combine at
// the end (3 barriers total, 33 KB LDS).
// ---------------------------------------------------------------------------
__global__ __launch_bounds__(256, 4) void flash_kernel(
    const bf16_t* __restrict__ Kf, const bf16_t* __restrict__ Vf,
    float* __restrict__ out)
{
  __shared__ struct {
    __align__(16) float Cb[2][4096];       // combine slots (O^T partials)
    __align__(16) float Lb[2][64][4];      // combine slots (l partials)
  } u;

  const int t    = threadIdx.x;
  const int w    = t >> 6;             // key-quarter 0..3
  const int lane = t & 63;
  const int quad = lane >> 4;
  const int l15  = lane & 15;
  const int kh   = w;

  const int bh = blockIdx.x;           // 0..31 (id%8 = bh%8 -> XCD locality)
  const int b  = bh >> 3, h = bh & 7;
  const int rowbase = blockIdx.y * 64; // 64 q-rows per block
  const int qtile   = rowbase >> 4;    // 16-row tile base

  const bf16_t* __restrict__ Kb = Kf + (size_t)bh * 128 * 2 * 512;
  const bf16_t* __restrict__ Vb = Vf + (size_t)bh * 64 * 4 * 512;

  // Resident Q fragments (coalesced frag loads; B-operand of S^T).
  bf16x8 qf[4][2];
#pragma unroll
  for (int nt = 0; nt < 4; ++nt)
#pragma unroll
    for (int kk = 0; kk < 2; ++kk)
      qf[nt][kk] = *(const bf16x8*)(Kb + ((size_t)(qtile + nt) * 2 + kk) * 512 + lane * 8);

  // Fixed max m_i = ||k_i||^2; lane's q-row for tile nt is nt*16+l15.
  float mlog[4];
#pragma unroll
  for (int nt = 0; nt < 4; ++nt) {
    float ss = 0.f;
#pragma unroll
    for (int kk = 0; kk < 2; ++kk)
#pragma unroll
      for (int j = 0; j < 8; ++j) {
        const float qv = (float)qf[nt][kk][j];
        ss = fmaf(qv, qv, ss);
      }
    ss += __shfl_xor(ss, 16, 64);
    ss += __shfl_xor(ss, 32, 64);
    mlog[nt] = ss * LOG2E;
  }

  f32x4 accot[4][4] = {};  // O^T [d-tile][qrow-tile], C-layout col=qrow=l15
  float lsum[4] = {0.f, 0.f, 0.f, 0.f};  // per qrow-tile, partial over quads

  // K frag loader: this wave's keys = kt*128 + kh*32 .. +31
  //   16-key tiles: kt*8 + kh*2 + {0,1}
  auto load_k = [&](int kt, bf16x8 (&dst)[2][2]) {
    const int kb = kt * 8 + kh * 2;
#pragma unroll
    for (int jt = 0; jt < 2; ++jt)
#pragma unroll
      for (int kk = 0; kk < 2; ++kk)
        dst[jt][kk] =
            *(const bf16x8*)(Kb + ((size_t)(kb + jt) * 2 + kk) * 512 + lane * 8);
  };

  // One tile: uses kcur (resident), prefetches kt+1 into knxt.
  auto body = [&](int kt, bf16x8 (&kcur)[2][2], bf16x8 (&knxt)[2][2]) {
    // V^T A-frag pairs for current tile.
    union { bf16x8 v8; s16x4 s4[2]; } vf[4];
    const int v32 = kt * 4 + kh;
#pragma unroll
    for (int dt = 0; dt < 4; ++dt)
      vf[dt].v8 = *(const bf16x8*)(Vb + ((size_t)v32 * 4 + dt) * 512 + lane * 8);

    // S^T = K . Q^T.
    f32x4 st[2][4] = {};
#pragma unroll
    for (int kk = 0; kk < 2; ++kk)
#pragma unroll
      for (int jt = 0; jt < 2; ++jt)
#pragma unroll
        for (int nt = 0; nt < 4; ++nt)
          st[jt][nt] = MFMA16(kcur[jt][kk], qf[nt][kk], st[jt][nt]);

    // Prefetch next K tile (clamped on last iter).
    load_k(kt + 1 < 16 ? kt + 1 : kt, knxt);

    // P = exp(S - m) -> K=16 B-frags, straight in registers.
    s16x4 pw[2][4];
#pragma unroll
    for (int jt = 0; jt < 2; ++jt)
#pragma unroll
      for (int nt = 0; nt < 4; ++nt) {
        union { bf16_t h[4]; s16x4 s; } pp;
#pragma unroll
        for (int reg = 0; reg < 4; ++reg) {
          const float p =
              __builtin_amdgcn_exp2f(fmaf(st[jt][nt][reg], LOG2E, -mlog[nt]));
          lsum[nt] += p;
          pp.h[reg] = (bf16_t)p;
        }
        pw[jt][nt] = pp.s;
      }

    // O^T += V^T . P^T (K=16, registers only).
#pragma unroll
    for (int jt = 0; jt < 2; ++jt)
#pragma unroll
      for (int dt = 0; dt < 4; ++dt)
#pragma unroll
        for (int nt = 0; nt < 4; ++nt)
          accot[dt][nt] = MFMA1K(vf[dt].s4[jt], pw[jt][nt], accot[dt][nt]);
  };

  bf16x8 kA[2][2], kB[2][2];
  load_k(0, kA);
#pragma unroll 1
  for (int kt = 0; kt < 16; kt += 2) {
    body(kt,     kA, kB);   // static buffer names -> no dynamic reg indexing
    body(kt + 1, kB, kA);
  }

  // 2-level tree combine across the 4 key-quarter waves.
  __syncthreads();
  if (w >= 2) {           // waves 2,3 dump to slots 0,1
    const int s = w - 2;
#pragma unroll
    for (int dt = 0; dt < 4; ++dt)
#pragma unroll
      for (int nt = 0; nt < 4; ++nt)
        *(f32x4*)(&u.Cb[s][((dt * 4 + nt) * 64 + lane) * 4]) = accot[dt][nt];
#pragma unroll
    for (int nt = 0; nt < 4; ++nt) u.Lb[s][lane][nt] = lsum[nt];
  }
  __syncthreads();
  if (w < 2) {            // waves 0,1 add slots 0,1
#pragma unroll
    for (int dt = 0; dt < 4; ++dt)
#pragma unroll
      for (int nt = 0; nt < 4; ++nt)
        accot[dt][nt] += *(const f32x4*)(&u.Cb[w][((dt * 4 + nt) * 64 + lane) * 4]);
#pragma unroll
    for (int nt = 0; nt < 4; ++nt) lsum[nt] += u.Lb[w][lane][nt];
  }
  __syncthreads();
  if (w == 1) {           // wave 1 dumps to slot 0
#pragma unroll
    for (int dt = 0; dt < 4; ++dt)
#pragma unroll
      for (int nt = 0; nt < 4; ++nt)
        *(f32x4*)(&u.Cb[0][((dt * 4 + nt) * 64 + lane) * 4]) = accot[dt][nt];
#pragma unroll
    for (int nt = 0; nt < 4; ++nt) u.Lb[0][lane][nt] = lsum[nt];
  }
  __syncthreads();
  if (w == 0) {
#pragma unroll
    for (int dt = 0; dt < 4; ++dt)
#pragma unroll
      for (int nt = 0; nt < 4; ++nt)
        accot[dt][nt] += *(const f32x4*)(&u.Cb[0][((dt * 4 + nt) * 64 + lane) * 4]);

    const float SCL = 0.044194173824159216f;  // 1/sqrt(512)
    float f[4];
#pragma unroll
    for (int nt = 0; nt < 4; ++nt) {
      float l = lsum[nt] + u.Lb[0][lane][nt];
      l += __shfl_xor(l, 16, 64);
      l += __shfl_xor(l, 32, 64);
      f[nt] = SCL / l;   // l of qrow nt*16+l15 — lane-uniform across regs
    }

    // O^T epilogue: contiguous f32x4 stores (d = dt*16+quad*4..+3).
#pragma unroll
    for (int nt = 0; nt < 4; ++nt) {
      const int n = rowbase + nt * 16 + l15;
      float* op = out + ((size_t)(b * NSEQ + n)) * EMB + h * HD;
#pragma unroll
      for (int dt = 0; dt < 4; ++dt) {
        f32x4 v = accot[dt][nt];
#pragma unroll
        for (int reg = 0; reg < 4; ++reg) v[reg] *= f[nt];
        *(f32x4*)(op + dt * 16 + quad * 4) = v;
      }
    }
  }
}

extern "C" void kernel_launch(void* const* d_in, const int* in_sizes, int n_in,
                              void* d_out, int out_size, void* d_ws, size_t ws_size,
                              hipStream_t stream) {
  const float* x  = (const float*)d_in[0];
  const float* Wk = (const float*)d_in[1];
  const float* bk = (const float*)d_in[2];
  const float* Wv = (const float*)d_in[3];
  const float* bv = (const float*)d_in[4];
  float* out = (float*)d_out;

  bf16_t* Kf = (bf16_t*)d_ws;                                   // 8 MB
  bf16_t* Vf = Kf + (size_t)BATCH * HEADS * NSEQ * HD;          // 8 MB

  dim3 pg(8192 / 128, 1024 / 128);
  proj_kernel<<<pg, 256, 0, stream>>>(x, Wk, bk, Wv, bv, Kf, Vf);

  dim3 fg(BATCH * HEADS, NSEQ / 64);
  flash_kernel<<<fg, 256, 0, stream>>>(Kf, Vf, out);
}

// Round 11
// 130.530 us; speedup vs baseline: 3.0619x; 3.0619x over previous
//
#include <hip/hip_runtime.h>

typedef __bf16 bf16_t;
typedef bf16_t bf16x8 __attribute__((ext_vector_type(8)));
typedef float f32x4 __attribute__((ext_vector_type(4)));

#define NSEQ 2048
#define EMB 512
#define HEADS 8
#define HD 64
#define BATCH 4
#define LOG2E 1.4426950408889634f

#define MFMA16(a, b, c) __builtin_amdgcn_mfma_f32_16x16x32_bf16(a, b, c, 0, 0, 0)

// Fragment-major layouts (frag = 64 lanes x 8 bf16, contiguous 1 KB):
//   Kf[((bh*128 + kt16)*2 + kk)*512 + lane*8 + j]
//       = K[bh][key = kt16*16 + (lane&15)][d = kk*32 + (lane>>4)*8 + j]
//   Vf[((bh*64 + kt32)*4 + dt)*512 + lane*8 + j]        (K=32 B-frags)
//       = V[bh][key = kt32*32 + (lane>>4)*8 + j][d = dt*16 + (lane&15)]

// ---------------------------------------------------------------------------
// Fused K/V projection GEMM with inline fp32->bf16 convert (R8-validated,
// byte-identical): C[8192,1024] = x @ [Wk;Wv]^T + [bk;bv].
// ---------------------------------------------------------------------------
__global__ __launch_bounds__(256, 2) void proj_kernel(
    const float* __restrict__ x,
    const float* __restrict__ Wk, const float* __restrict__ bk,
    const float* __restrict__ Wv, const float* __restrict__ bv,
    bf16_t* __restrict__ Kf, bf16_t* __restrict__ Vf)
{
  __shared__ union {
    struct {
      __align__(16) bf16_t A[2][128][40];   // [kk-half][row][32 el + pad]
      __align__(16) bf16_t B[2][128][40];
    } s;
    __align__(16) bf16_t T[128][136];       // epilogue relayout buffer
  } u;

  const int t    = threadIdx.x;
  const int w    = t >> 6;
  const int lane = t & 63;
  const int quad = lane >> 4;
  const int l15  = lane & 15;
  const int wr   = w >> 1, wc = w & 1;
  const int m0   = blockIdx.x * 128;
  const int n0   = blockIdx.y * 128;        // stacked feature base 0..896
  const int zz   = (blockIdx.y >= 4);       // 0: K-features, 1: V-features
  const float* __restrict__ W = zz ? Wv : Wk;
  const int nW = n0 - zz * 512;             // row base within W

  const int sr = t >> 3;        // staging row 0..31 (x4 groups)
  const int sj = t & 7;         // 8-el chunk 0..7 within 64-el k slab
  const int sb = sj >> 2, sc = (sj & 3) * 8;

  float4 pa[4][2], pb[4][2];
  auto prefetch = [&](int k0) {
#pragma unroll
    for (int i = 0; i < 4; ++i) {
      const float* xa = x + (size_t)(m0 + sr + i * 32) * EMB + k0 + sj * 8;
      const float* wa = W + (size_t)(nW + sr + i * 32) * EMB + k0 + sj * 8;
      pa[i][0] = *(const float4*)xa; pa[i][1] = *(const float4*)(xa + 4);
      pb[i][0] = *(const float4*)wa; pb[i][1] = *(const float4*)(wa + 4);
    }
  };
  auto pack8 = [](float4 a, float4 b) -> bf16x8 {
    bf16x8 v;
    v[0] = (bf16_t)a.x; v[1] = (bf16_t)a.y; v[2] = (bf16_t)a.z; v[3] = (bf16_t)a.w;
    v[4] = (bf16_t)b.x; v[5] = (bf16_t)b.y; v[6] = (bf16_t)b.z; v[7] = (bf16_t)b.w;
    return v;
  };

  f32x4 acc[4][4] = {};
  prefetch(0);

  for (int it = 0; it < 8; ++it) {
    __syncthreads();
#pragma unroll
    for (int i = 0; i < 4; ++i) {
      *(bf16x8*)(&u.s.A[sb][sr + i * 32][sc]) = pack8(pa[i][0], pa[i][1]);
      *(bf16x8*)(&u.s.B[sb][sr + i * 32][sc]) = pack8(pb[i][0], pb[i][1]);
    }
    __syncthreads();
    if (it < 7) prefetch((it + 1) * 64);

    bf16x8 af[4][2], bf[4][2];
#pragma unroll
    for (int mt = 0; mt < 4; ++mt)
#pragma unroll
      for (int kk = 0; kk < 2; ++kk)
        af[mt][kk] = *(const bf16x8*)(&u.s.A[kk][wr * 64 + mt * 16 + l15][quad * 8]);
#pragma unroll
    for (int nt = 0; nt < 4; ++nt)
#pragma unroll
      for (int kk = 0; kk < 2; ++kk)
        bf[nt][kk] = *(const bf16x8*)(&u.s.B[kk][wc * 64 + nt * 16 + l15][quad * 8]);
#pragma unroll
    for (int kk = 0; kk < 2; ++kk)
#pragma unroll
      for (int mt = 0; mt < 4; ++mt)
#pragma unroll
        for (int nt = 0; nt < 4; ++nt)
          acc[mt][nt] = MFMA16(af[mt][kk], bf[nt][kk], acc[mt][nt]);
  }

  __syncthreads();  // staging LDS -> relayout buffer reuse

  // Stage 1: +bias, bf16, into LDS (K: row-major [n][feat]; V: [feat][n]).
#pragma unroll
  for (int mt = 0; mt < 4; ++mt) {
#pragma unroll
    for (int nt = 0; nt < 4; ++nt) {
      const int F = wc * 64 + nt * 16 + l15;       // local feature 0..127
      const int c = n0 + F;                        // stacked feature 0..1023
      const float bb = zz ? bv[c - 512] : bk[c];
#pragma unroll
      for (int reg = 0; reg < 4; ++reg) {
        const int R = wr * 64 + mt * 16 + quad * 4 + reg;  // local row 0..127
        const float v = acc[mt][nt][reg] + bb;
        if (!zz) u.T[R][F] = (bf16_t)v;
        else     u.T[F][R] = (bf16_t)v;
      }
    }
  }
  __syncthreads();

  // Stage 2: fragment-major coalesced stores (1 KB per wave-store).
  if (!zz) {
    // 32 frags: hL(2) x kk(2) x ktl(8)
#pragma unroll
    for (int i = 0; i < 8; ++i) {
      const int fi  = i * 4 + w;
      const int hL  = fi >> 4, kk = (fi >> 3) & 1, ktl = fi & 7;
      const bf16x8 v = *(const bf16x8*)(&u.T[ktl * 16 + l15][hL * 64 + kk * 32 + quad * 8]);
      const int gr = m0 + ktl * 16 + l15;          // global key row
      const int b = gr >> 11, n = gr & (NSEQ - 1);
      const int bh = b * HEADS + (n0 >> 6) + hL;
      bf16_t* dst = Kf + (((size_t)(bh * 128 + (n >> 4)) * 2 + kk)) * 512 + lane * 8;
      *(bf16x8*)dst = v;
    }
  } else {
    // 32 frags: hL(2) x dt(4) x k32l(4)
#pragma unroll
    for (int i = 0; i < 8; ++i) {
      const int fi   = i * 4 + w;
      const int hL   = fi >> 4, dt = (fi >> 2) & 3, k32l = fi & 3;
      const bf16x8 v = *(const bf16x8*)(&u.T[hL * 64 + dt * 16 + l15][k32l * 32 + quad * 8]);
      const int gr = m0 + k32l * 32;               // key base (same b for block)
      const int b = gr >> 11, n = gr & (NSEQ - 1);
      const int bh = b * HEADS + ((n0 - 512) >> 6) + hL;
      bf16_t* dst = Vf + (((size_t)(bh * 64 + (n >> 5)) * 4 + dt)) * 512 + lane * 8;
      *(bf16x8*)dst = v;
    }
  }
}

// ---------------------------------------------------------------------------
// Flash attention, Q = K, fixed max m_i = ||k_i||^2, S^T trick, R8 loop
// byte-for-byte (fragment-major global loads, static double-buffered K,
// per-wave LDS P relayout, K=32 PV, ones-MFMA l).
// R11: 4-WAY KEY SPLIT for occupancy WITHOUT register pressure — the 4
// waves of a block share the same 64 q-rows and take disjoint 512-key
// quarters (16 iters each). Grid (32 bh, 32 qtiles) = 1024 blocks ->
// 4 blocks/CU (LDS 40 KB binds; VGPR ~100 untouched, launch bounds stay
// (256,2) -- R10's (256,4) cap caused catastrophic scratch spills).
// 2-level LDS tree combine at the end.
// ---------------------------------------------------------------------------
__global__ __launch_bounds__(256, 2) void flash_kernel(
    const bf16_t* __restrict__ Kf, const bf16_t* __restrict__ Vf,
    float* __restrict__ out)
{
  __shared__ union {
    __align__(16) bf16_t Pl[4][64][40];      // per-wave P [qrow][32 keys + pad]
    struct {
      __align__(16) float Cb[2][4096];       // combine slots (O partials)
      __align__(16) float Lb[2][64][16];     // combine slots (l partials)
    } c;
  } u;

  const int t    = threadIdx.x;
  const int w    = t >> 6;             // key-quarter 0..3
  const int lane = t & 63;
  const int quad = lane >> 4;
  const int l15  = lane & 15;
  const int kh   = w;

  const int bh = blockIdx.x;           // 0..31 (id%8 = bh%8 -> XCD locality)
  const int b  = bh >> 3, h = bh & 7;
  const int rowbase = blockIdx.y * 64; // 64 q-rows per block (shared by waves)
  const int qtile   = rowbase >> 4;    // 16-row tile base

  const bf16_t* __restrict__ Kb = Kf + (size_t)bh * 128 * 2 * 512;
  const bf16_t* __restrict__ Vb = Vf + (size_t)bh * 64 * 4 * 512;

  // Resident Q fragments (coalesced frag loads; B-operand of S^T).
  bf16x8 qf[4][2];
#pragma unroll
  for (int nt = 0; nt < 4; ++nt)
#pragma unroll
    for (int kk = 0; kk < 2; ++kk)
      qf[nt][kk] = *(const bf16x8*)(Kb + ((size_t)(qtile + nt) * 2 + kk) * 512 + lane * 8);

  // Fixed max m_i = ||k_i||^2; lane's q-row for tile nt is nt*16+l15.
  float mlog[4];
#pragma unroll
  for (int nt = 0; nt < 4; ++nt) {
    float ss = 0.f;
#pragma unroll
    for (int kk = 0; kk < 2; ++kk)
#pragma unroll
      for (int j = 0; j < 8; ++j) {
        const float qv = (float)qf[nt][kk][j];
        ss = fmaf(qv, qv, ss);
      }
    ss += __shfl_xor(ss, 16, 64);
    ss += __shfl_xor(ss, 32, 64);
    mlog[nt] = ss * LOG2E;
  }

  bf16x8 ones;
#pragma unroll
  for (int j = 0; j < 8; ++j) ones[j] = (bf16_t)1.0f;

  f32x4 acco[4][4] = {};   // [row-tile][d-tile]
  f32x4 accll[4]   = {};   // l partials via ones-MFMA (C-layout)

  // K frag loader: this wave's keys = kt*128 + kh*32 .. +31
  //   16-key tiles: kt*8 + kh*2 + {0,1}
  auto load_k = [&](int kt, bf16x8 (&dst)[2][2]) {
    const int kb = kt * 8 + kh * 2;
#pragma unroll
    for (int jt = 0; jt < 2; ++jt)
#pragma unroll
      for (int kk = 0; kk < 2; ++kk)
        dst[jt][kk] =
            *(const bf16x8*)(Kb + ((size_t)(kb + jt) * 2 + kk) * 512 + lane * 8);
  };

  // One tile: uses kcur (resident), prefetches kt+1 into knxt.
  auto body = [&](int kt, bf16x8 (&kcur)[2][2], bf16x8 (&knxt)[2][2]) {
    // V frags (K=32 B-frags) for current tile.
    bf16x8 vf[4];
    const int v32 = kt * 4 + kh;
#pragma unroll
    for (int dt = 0; dt < 4; ++dt)
      vf[dt] = *(const bf16x8*)(Vb + ((size_t)v32 * 4 + dt) * 512 + lane * 8);

    // S^T = K . Q^T.
    f32x4 st[2][4] = {};
#pragma unroll
    for (int kk = 0; kk < 2; ++kk)
#pragma unroll
      for (int jt = 0; jt < 2; ++jt)
#pragma unroll
        for (int nt = 0; nt < 4; ++nt)
          st[jt][nt] = MFMA16(kcur[jt][kk], qf[nt][kk], st[jt][nt]);

    // Prefetch next K tile (clamped on last iter).
    load_k(kt + 1 < 16 ? kt + 1 : kt, knxt);

    // P = exp(S - m); b64 scatter to per-wave LDS (C->A relayout).
#pragma unroll
    for (int jt = 0; jt < 2; ++jt)
#pragma unroll
      for (int nt = 0; nt < 4; ++nt) {
        union { bf16_t hx[4]; uint2 u2; } pw;
#pragma unroll
        for (int reg = 0; reg < 4; ++reg) {
          const float p =
              __builtin_amdgcn_exp2f(fmaf(st[jt][nt][reg], LOG2E, -mlog[nt]));
          pw.hx[reg] = (bf16_t)p;
        }
        *(uint2*)(&u.Pl[w][nt * 16 + l15][jt * 16 + quad * 4]) = pw.u2;
      }

    // P back in A-layout; O += P V, l += P . 1.
    bf16x8 pf[4];
#pragma unroll
    for (int rt = 0; rt < 4; ++rt)
      pf[rt] = *(const bf16x8*)(&u.Pl[w][rt * 16 + l15][quad * 8]);
#pragma unroll
    for (int rt = 0; rt < 4; ++rt) {
      accll[rt] = MFMA16(pf[rt], ones, accll[rt]);
#pragma unroll
      for (int dt = 0; dt < 4; ++dt)
        acco[rt][dt] = MFMA16(pf[rt], vf[dt], acco[rt][dt]);
    }
  };

  bf16x8 kA[2][2], kB[2][2];
  load_k(0, kA);
  for (int kt = 0; kt < 16; kt += 2) {
    body(kt,     kA, kB);   // static buffer names -> no dynamic reg indexing
    body(kt + 1, kB, kA);
  }

  // 2-level tree combine across the 4 key-quarter waves.
  __syncthreads();
  if (w >= 2) {           // waves 2,3 dump to slots 0,1
    const int s = w - 2;
#pragma unroll
    for (int rt = 0; rt < 4; ++rt) {
#pragma unroll
      for (int dt = 0; dt < 4; ++dt)
        *(f32x4*)(&u.c.Cb[s][((rt * 4 + dt) * 64 + lane) * 4]) = acco[rt][dt];
      *(f32x4*)(&u.c.Lb[s][lane][rt * 4]) = accll[rt];
    }
  }
  __syncthreads();
  if (w < 2) {            // waves 0,1 add slots 0,1
#pragma unroll
    for (int rt = 0; rt < 4; ++rt) {
#pragma unroll
      for (int dt = 0; dt < 4; ++dt)
        acco[rt][dt] += *(const f32x4*)(&u.c.Cb[w][((rt * 4 + dt) * 64 + lane) * 4]);
      accll[rt] += *(const f32x4*)(&u.c.Lb[w][lane][rt * 4]);
    }
  }
  __syncthreads();
  if (w == 1) {           // wave 1 dumps to slot 0
#pragma unroll
    for (int rt = 0; rt < 4; ++rt) {
#pragma unroll
      for (int dt = 0; dt < 4; ++dt)
        *(f32x4*)(&u.c.Cb[0][((rt * 4 + dt) * 64 + lane) * 4]) = acco[rt][dt];
      *(f32x4*)(&u.c.Lb[0][lane][rt * 4]) = accll[rt];
    }
  }
  __syncthreads();
  if (w == 0) {
#pragma unroll
    for (int rt = 0; rt < 4; ++rt) {
#pragma unroll
      for (int dt = 0; dt < 4; ++dt)
        acco[rt][dt] += *(const f32x4*)(&u.c.Cb[0][((rt * 4 + dt) * 64 + lane) * 4]);
      accll[rt] += *(const f32x4*)(&u.c.Lb[0][lane][rt * 4]);
    }

    const float SCL = 0.044194173824159216f;  // 1/sqrt(512)
    // accll[rt][reg] = l of q-row rt*16+quad*4+reg — already acco-aligned.
#pragma unroll
    for (int rt = 0; rt < 4; ++rt)
#pragma unroll
      for (int reg = 0; reg < 4; ++reg) {
        const float f = SCL / accll[rt][reg];
        const int n = rowbase + rt * 16 + quad * 4 + reg;
#pragma unroll
        for (int dt = 0; dt < 4; ++dt)
          out[((size_t)(b * NSEQ + n)) * EMB + h * HD + dt * 16 + l15] =
              acco[rt][dt][reg] * f;
      }
  }
}

extern "C" void kernel_launch(void* const* d_in, const int* in_sizes, int n_in,
                              void* d_out, int out_size, void* d_ws, size_t ws_size,
                              hipStream_t stream) {
  const float* x  = (const float*)d_in[0];
  const float* Wk = (const float*)d_in[1];
  const float* bk = (const float*)d_in[2];
  const float* Wv = (const float*)d_in[3];
  const float* bv = (const float*)d_in[4];
  float* out = (float*)d_out;

  bf16_t* Kf = (bf16_t*)d_ws;                                   // 8 MB
  bf16_t* Vf = Kf + (size_t)BATCH * HEADS * NSEQ * HD;          // 8 MB

  dim3 pg(8192 / 128, 1024 / 128);
  proj_kernel<<<pg, 256, 0, stream>>>(x, Wk, bk, Wv, bv, Kf, Vf);

  dim3 fg(BATCH * HEADS, NSEQ / 64);
  flash_kernel<<<fg, 256, 0, stream>>>(Kf, Vf, out);
}